// Round 12
// baseline (3417.926 us; speedup 1.0000x reference)
//
#include <hip/hip_runtime.h>
#include <stdint.h>

// Problem dims
#define NB 512   // batch N
#define NM 64    // rows of G
#define NT 32    // tx antennas (and scan steps)
#define NK 8     // symbol alphabet
#define NS 256   // MC samples
#define LQP 9    // padded LDS row stride for lq (dwords)
#define SYF 36   // float stride for symbol rows (144B: 16B-aligned -> b128 reads)

// JAX threefry_partitionable=True, verified absmax 1.0 (rounds 1/6/7/8/10/11).
// Rotate as v_alignbit_b32 (1 op, bit-exact): rotl(x,r) = rotr(x, 32-r).
#define ROTL(x, r) __builtin_amdgcn_alignbit((x), (x), 32 - (r))

// Raw HW transcendentals (v_exp_f32 / v_log_f32 are base-2 on gfx950).
#if __has_builtin(__builtin_amdgcn_exp2f)
#define EXP2(x) __builtin_amdgcn_exp2f(x)
#else
#define EXP2(x) exp2f(x)
#endif
#if __has_builtin(__builtin_amdgcn_logf)
#define LOG2(x) __builtin_amdgcn_logf(x)
#else
#define LOG2(x) __log2f(x)
#endif

__device__ __forceinline__ uint2 tf2x32(uint32_t k0, uint32_t k1, uint32_t x0, uint32_t x1) {
  uint32_t k2 = k0 ^ k1 ^ 0x1BD11BDAu;
#define TFRND(r) { x0 += x1; x1 = ROTL(x1, r); x1 ^= x0; }
  x0 += k0; x1 += k1;
  TFRND(13) TFRND(15) TFRND(26) TFRND(6)
  x0 += k1; x1 += k2 + 1u;
  TFRND(17) TFRND(29) TFRND(16) TFRND(24)
  x0 += k2; x1 += k0 + 2u;
  TFRND(13) TFRND(15) TFRND(26) TFRND(6)
  x0 += k0; x1 += k1 + 3u;
  TFRND(17) TFRND(29) TFRND(16) TFRND(24)
  x0 += k1; x1 += k2 + 4u;
  TFRND(13) TFRND(15) TFRND(26) TFRND(6)
  x0 += k2; x1 += k0 + 5u;
#undef TFRND
  return make_uint2(x0, x1);
}

// One block per batch element n; all 32 scan steps fused; everything in LDS.
// min-waves=8 -> 2 blocks/CU (proven round 11: occ 48->74%, -27% dur).
// Round 12 change: ROLL the d-loop and dot j-loop. Round 11's unrolled
// sampling body was ~64 inlined threefry evals ~= 42 KB of code — past the
// 32 KB L1 I-cache; instruction fetch was the suspected 1.4x-over-floor gap.
__global__ __launch_bounds__(1024, 8) void mfs_fused(
    const float* __restrict__ log_qi, const float* __restrict__ G,
    const float* __restrict__ s2r, const float* __restrict__ alpha_p,
    float* __restrict__ lq_out) {
  __shared__ float sg[NM * NT];          // 8 KiB
  __shared__ float lqs[NT * LQP];        // padded 32x9 dwords
  __shared__ float symf[NS * SYF];       // 36 KiB: symbols as floats, xi-col = 0
  __shared__ double red[16][NK];         // wave partials
  __shared__ uint32_t keys2[NT * 2];

  const int n = blockIdx.x;
  const int tid = threadIdx.x;

  {
    float s2v = s2r[n];
    float2 g2 = ((const float2*)(G + (size_t)n * NM * NT))[tid];
    ((float2*)sg)[tid] = make_float2(s2v * g2.x, s2v * g2.y);   // exact f32 mul
  }
  if (tid < NT * NK) lqs[(tid >> 3) * LQP + (tid & 7)] = log_qi[(size_t)n * NT * NK + tid];
  if (tid < NT) {
    // split foldlike: key_i = threefry2x32(parent=(0,42), hi=0, lo=i)
    uint2 r = tf2x32(0u, 42u, 0u, (uint32_t)tid);
    keys2[2 * tid] = r.x; keys2[2 * tid + 1] = r.y;
  }
  __syncthreads();

  // Init-shift rows 1..31 once (row r's shift first applies at end of step 0 in
  // the reference; re-shifts of settled rows are bit-exact no-ops). Row 0's
  // step-0 oldv must stay unshifted. Sampling is shift-invariant.
  if (tid < NT * NK) {
    int t2 = tid >> 3;
    float vv = lqs[t2 * LQP + (tid & 7)];
    float mx = vv;
    mx = fmaxf(mx, __shfl_xor(mx, 1, 64));
    mx = fmaxf(mx, __shfl_xor(mx, 2, 64));
    mx = fmaxf(mx, __shfl_xor(mx, 4, 64));
    if (t2 > 0) lqs[t2 * LQP + (tid & 7)] = vv - mx;
  }
  __syncthreads();

  const float alpha = *alpha_p;
  const int t = tid & 31;            // sampling: antenna owned by this thread
  const int sgrp = tid >> 5;         // sampling: s-group 0..31
  const int ss = tid & 255;          // update: sample row
  const int mg = tid >> 8;           // update: m-group 0..3 (16 m's each)
  const float TINY = 1.17549435e-38f;
  const float K2 = 2.4554669595930158f;   // 1.702 * log2(e)

  for (int xi = 0; xi < NT; ++xi) {
    // ---------- sample: 8 draws/thread ----------
    // argmax_k(l+g), g=-log(-log(u))  <=>  argmin_k (-ln u)*exp(-l)
    //  = argmin_k (-log2 u) * Fp[k],  Fp[k] = ln2*exp(-l[k]) > 0 (score >= 0).
    // Packed-uint argmin keeps JAX's first-max tie-break.
    uint32_t kA = keys2[2 * xi], kB = keys2[2 * xi + 1];
    float Fp[NK];
#pragma unroll
    for (int k = 0; k < NK; ++k) {
      float l = lqs[t * LQP + k];
      Fp[k] = EXP2(fmaf(l, -1.4426950408889634f, -0.5287663729448977f));
    }
    bool isxi = (t == xi);
#pragma unroll 1        // ROLLED: keep sampling body I$-resident (~700 instr)
    for (int d = 0; d < 8; ++d) {
      int s = sgrp + (d << 5);
      uint32_t p = ((uint32_t)((s * NB + n) * NT + t)) << 3;  // flat (S,N,T,K)
      uint32_t best = 0xffffffffu;
#pragma unroll
      for (int k = 0; k < NK; ++k) {
        uint2 r = tf2x32(kA, kB, 0u, p + (uint32_t)k);
        uint32_t bits = r.x ^ r.y;
        float f = __uint_as_float((bits >> 9) | 0x3f800000u) - 1.0f;
        float u = fmaxf(f, TINY);           // == fmax(TINY, f+TINY) bit-exact
        float score = (-LOG2(u)) * Fp[k];   // neg folds into v_mul src modifier
        uint32_t sv = (__float_as_uint(score) & ~7u) | (uint32_t)k;
        best = min(best, sv);
      }
      // store symbol as float; antenna xi stores 0.0 (exclusion baked in)
      float bi = (float)(int)(best & 7u);
      float symval = fmaf(bi, 2.0f, -7.0f);                   // 2*bi - 7, exact
      symf[s * SYF + t] = isxi ? 0.0f : symval;
    }
    __syncthreads();

    // ---------- update: thread = (sample ss, m-group mg) ----------
    // dot products: j-outer over t-quads; per-acc[mi] FMA order = t ascending,
    // bit-identical chain to rounds 10/11.
    const float* sgp = sg + mg * 16 * NT;
    const float* myrow = symf + ss * SYF;
    float acc[16];
#pragma unroll
    for (int mi = 0; mi < 16; ++mi) acc[mi] = 0.0f;
#pragma unroll 1        // ROLLED: ~85-instr body, lets scheduler pipeline reads
    for (int j = 0; j < 8; ++j) {
      float4 sp4 = *(const float4*)(myrow + 4 * j);           // ds_read_b128
#pragma unroll
      for (int mi = 0; mi < 16; ++mi) {
        float4 g4 = ((const float4*)(sgp + mi * NT))[j];      // wave-uniform
        acc[mi] = fmaf(g4.x, sp4.x, acc[mi]);
        acc[mi] = fmaf(g4.y, sp4.y, acc[mi]);
        acc[mi] = fmaf(g4.z, sp4.z, acc[mi]);
        acc[mi] = fmaf(g4.w, sp4.w, acc[mi]);
      }
    }
    // log-sigmoid in log2 domain: ls(z)/ln2 = min(zb,0) - log2(1+exp2(-|zb|)),
    // zb = term*K2; ln2 folded into the final mean constant.
    float lp[NK];
#pragma unroll
    for (int k = 0; k < NK; ++k) lp[k] = 0.0f;
#pragma unroll
    for (int mi = 0; mi < 16; ++mi) {
      float base2 = acc[mi] * K2;
      float c2 = sgp[mi * NT + xi] * K2;
#pragma unroll
      for (int k = 0; k < NK; ++k) {
        float zb = fmaf(c2, (float)(2 * k - 7), base2);
        float e2 = EXP2(-fabsf(zb));                          // -|x| src mods
        lp[k] += fminf(zb, 0.0f) - LOG2(1.0f + e2);
      }
    }

    // reduction: f64 tree, structure/order identical to rounds 6-11 (proven)
    double v[NK];
#pragma unroll
    for (int k = 0; k < NK; ++k) v[k] = (double)lp[k];
#pragma unroll
    for (int off = 32; off >= 1; off >>= 1) {
#pragma unroll
      for (int k = 0; k < NK; ++k) v[k] += __shfl_down(v[k], off, 64);
    }
    int wave = tid >> 6, lane = tid & 63;
    if (lane == 0) {
#pragma unroll
      for (int k = 0; k < NK; ++k) red[wave][k] = v[k];
    }
    __syncthreads();
    if (tid < NK) {
      double sum = 0.0;
#pragma unroll
      for (int q = 0; q < 16; ++q) sum += red[q][tid];
      float ex = (float)(sum * 0.0027076061740622863);        // ln2/256
      float oldv = lqs[xi * LQP + tid];
      float newv = (1.0f - alpha) * oldv + alpha * ex;
      // per-row max shift for the just-updated row (lanes 0..7, in-register)
      float mx = newv;
      mx = fmaxf(mx, __shfl_xor(mx, 1, 64));
      mx = fmaxf(mx, __shfl_xor(mx, 2, 64));
      mx = fmaxf(mx, __shfl_xor(mx, 4, 64));
      lqs[xi * LQP + tid] = newv - mx;
    }
    __syncthreads();
  }

  if (tid < NT * NK)
    lq_out[(size_t)n * NT * NK + tid] = lqs[(tid >> 3) * LQP + (tid & 7)];
}

extern "C" void kernel_launch(void* const* d_in, const int* in_sizes, int n_in,
                              void* d_out, int out_size, void* d_ws, size_t ws_size,
                              hipStream_t stream) {
  const float* log_qi = (const float*)d_in[0];
  const float* G      = (const float*)d_in[1];
  const float* s2r    = (const float*)d_in[2];
  const float* alpha  = (const float*)d_in[3];
  float* lq = (float*)d_out;
  mfs_fused<<<NB, 1024, 0, stream>>>(log_qi, G, s2r, alpha, lq);
}

// Round 13
// 2462.894 us; speedup vs baseline: 1.3878x; 1.3878x over previous
//
#include <hip/hip_runtime.h>
#include <stdint.h>

// Problem dims
#define NB 512   // batch N
#define NM 64    // rows of G
#define NT 32    // tx antennas (and scan steps)
#define NK 8     // symbol alphabet
#define NS 256   // MC samples
#define LQP 9    // padded LDS row stride for lq (dwords)
#define SYB 40   // ushort stride for symbol rows (80B: 16B-aligned -> b128 A-frags)
#define SGB 40   // ushort stride for bf16 sG tables

// JAX threefry_partitionable=True, verified absmax 1.0 (rounds 1/6/7/8/10/11).
#define ROTL(x, r) __builtin_amdgcn_alignbit((x), (x), 32 - (r))

#if __has_builtin(__builtin_amdgcn_exp2f)
#define EXP2(x) __builtin_amdgcn_exp2f(x)
#else
#define EXP2(x) exp2f(x)
#endif
#if __has_builtin(__builtin_amdgcn_logf)
#define LOG2(x) __builtin_amdgcn_logf(x)
#else
#define LOG2(x) __log2f(x)
#endif

typedef __attribute__((ext_vector_type(8))) short bf16x8;    // 8 bf16 (4 VGPRs)
typedef __attribute__((ext_vector_type(16))) float f32x16;   // MFMA 32x32 acc

__device__ __forceinline__ uint2 tf2x32(uint32_t k0, uint32_t k1, uint32_t x0, uint32_t x1) {
  uint32_t k2 = k0 ^ k1 ^ 0x1BD11BDAu;
#define TFRND(r) { x0 += x1; x1 = ROTL(x1, r); x1 ^= x0; }
  x0 += k0; x1 += k1;
  TFRND(13) TFRND(15) TFRND(26) TFRND(6)
  x0 += k1; x1 += k2 + 1u;
  TFRND(17) TFRND(29) TFRND(16) TFRND(24)
  x0 += k2; x1 += k0 + 2u;
  TFRND(13) TFRND(15) TFRND(26) TFRND(6)
  x0 += k0; x1 += k1 + 3u;
  TFRND(17) TFRND(29) TFRND(16) TFRND(24)
  x0 += k1; x1 += k2 + 4u;
  TFRND(13) TFRND(15) TFRND(26) TFRND(6)
  x0 += k2; x1 += k0 + 5u;
#undef TFRND
  return make_uint2(x0, x1);
}

// RNE f32 -> bf16 bits (no inf/nan in our data)
__device__ __forceinline__ uint32_t rne_bf16(float x) {
  uint32_t u = __float_as_uint(x);
  return (u + 0x7fffu + ((u >> 16) & 1u)) >> 16;
}

// One block per batch element n; all 32 scan steps fused; everything in LDS.
// Dot product via v_mfma_f32_32x32x16_bf16 with 3-way bf16 split of sG
// (hi+lo+lo2: residual ~2^-25 rel — same rounding class as the f32 FMA chain).
// 16 waves = 8 s-tiles x 2 m-tiles of C[256s x 64m] = sym[256x32] sG^T[32x64].
__global__ __launch_bounds__(1024, 8) void mfs_fused(
    const float* __restrict__ log_qi, const float* __restrict__ G,
    const float* __restrict__ s2r, const float* __restrict__ alpha_p,
    float* __restrict__ lq_out) {
  __shared__ float sgT[NT * NM];         // [t][m] f32: conflict-free c2 reads (8KB)
  __shared__ ushort sgh[NM * SGB];       // bf16 hi   [m][t], stride 40 (5KB)
  __shared__ ushort sgl[NM * SGB];       // bf16 lo
  __shared__ ushort sgl2[NM * SGB];      // bf16 lo2
  __shared__ ushort symb[NS * SYB];      // bf16 symbols [s][t], xi-col = 0 (20KB)
  __shared__ float lqs[NT * LQP];
  __shared__ double red[16][NK];
  __shared__ uint32_t keys2[NT * 2];

  const int n = blockIdx.x;
  const int tid = threadIdx.x;

  {
    // sG = s2r[n]*G[n] (exact f32 mul); split into bf16 hi/lo/lo2 + transposed f32
    float s2v = s2r[n];
    float2 g2 = ((const float2*)(G + (size_t)n * NM * NT))[tid];
#pragma unroll
    for (int e = 0; e < 2; ++e) {
      int i = 2 * tid + e;
      int m = i >> 5, t = i & 31;
      float x = s2v * (e ? g2.y : g2.x);
      uint32_t h = rne_bf16(x);
      float hf = __uint_as_float(h << 16);
      float r1 = x - hf;                      // exact
      uint32_t l = rne_bf16(r1);
      float lf = __uint_as_float(l << 16);
      float r2 = r1 - lf;                     // exact
      uint32_t l2 = rne_bf16(r2);
      sgh[m * SGB + t]  = (ushort)h;
      sgl[m * SGB + t]  = (ushort)l;
      sgl2[m * SGB + t] = (ushort)l2;
      sgT[t * NM + m] = x;
    }
  }
  if (tid < NT * NK) lqs[(tid >> 3) * LQP + (tid & 7)] = log_qi[(size_t)n * NT * NK + tid];
  if (tid < NT) {
    uint2 r = tf2x32(0u, 42u, 0u, (uint32_t)tid);   // split foldlike
    keys2[2 * tid] = r.x; keys2[2 * tid + 1] = r.y;
  }
  __syncthreads();

  // Init-shift rows 1..31 once (proven bit-exact reorganization, rounds 10/11)
  if (tid < NT * NK) {
    int t2 = tid >> 3;
    float vv = lqs[t2 * LQP + (tid & 7)];
    float mx = vv;
    mx = fmaxf(mx, __shfl_xor(mx, 1, 64));
    mx = fmaxf(mx, __shfl_xor(mx, 2, 64));
    mx = fmaxf(mx, __shfl_xor(mx, 4, 64));
    if (t2 > 0) lqs[t2 * LQP + (tid & 7)] = vv - mx;
  }
  __syncthreads();

  const float alpha = *alpha_p;
  const int t = tid & 31;            // sampling: antenna owned by this thread
  const int sgrp = tid >> 5;         // sampling: s-group 0..31
  const int lane = tid & 63;
  const int wid = tid >> 6;          // wave 0..15
  const int s_tile = wid & 7;        // MFMA: C-row tile (samples)
  const int m_tile = wid >> 3;       // MFMA: C-col tile (G rows)
  const int lm = lane & 31;          // A-row within tile / B-col within tile
  const int kh = lane >> 5;          // k-half (8 elems each)
  const int sA = s_tile * 32 + lm;   // my A (sym) row
  const int mB = m_tile * 32 + lm;   // my B (sG) column = output m
  const float TINY = 1.17549435e-38f;
  const float K2 = 2.4554669595930158f;   // 1.702 * log2(e)

  for (int xi = 0; xi < NT; ++xi) {
    // ---------- sample: 8 draws/thread (bit-exact path, unchanged from R11) ----
    uint32_t kA = keys2[2 * xi], kB = keys2[2 * xi + 1];
    float Fp[NK];
#pragma unroll
    for (int k = 0; k < NK; ++k) {
      float l = lqs[t * LQP + k];
      Fp[k] = EXP2(fmaf(l, -1.4426950408889634f, -0.5287663729448977f));
    }
    bool isxi = (t == xi);
#pragma unroll
    for (int d = 0; d < 8; ++d) {
      int s = sgrp + (d << 5);
      uint32_t p = ((uint32_t)((s * NB + n) * NT + t)) << 3;  // flat (S,N,T,K)
      uint32_t best = 0xffffffffu;
#pragma unroll
      for (int k = 0; k < NK; ++k) {
        uint2 r = tf2x32(kA, kB, 0u, p + (uint32_t)k);
        uint32_t bits = r.x ^ r.y;
        float f = __uint_as_float((bits >> 9) | 0x3f800000u) - 1.0f;
        float u = fmaxf(f, TINY);
        float score = (-LOG2(u)) * Fp[k];
        uint32_t sv = (__float_as_uint(score) & ~7u) | (uint32_t)k;
        best = min(best, sv);
      }
      float bi = (float)(int)(best & 7u);
      float symval = fmaf(bi, 2.0f, -7.0f);                   // 2*bi - 7, exact
      // bf16 bits exact (<=4 mantissa bits); xi column stores 0 (exclusion)
      symb[s * SYB + t] = isxi ? (ushort)0 : (ushort)(__float_as_uint(symval) >> 16);
    }
    __syncthreads();

    // ---------- update: MFMA dot ----------
    f32x16 acc;
#pragma unroll
    for (int i = 0; i < 16; ++i) acc[i] = 0.0f;
#pragma unroll
    for (int c = 0; c < 2; ++c) {
      int ko = c * 16 + kh * 8;                               // k = t offset
      bf16x8 a   = *(const bf16x8*)(symb + sA * SYB + ko);    // ds_read_b128
      bf16x8 bh  = *(const bf16x8*)(sgh  + mB * SGB + ko);
      bf16x8 bl  = *(const bf16x8*)(sgl  + mB * SGB + ko);
      bf16x8 bl2 = *(const bf16x8*)(sgl2 + mB * SGB + ko);
      acc = __builtin_amdgcn_mfma_f32_32x32x16_bf16(a, bh,  acc, 0, 0, 0);
      acc = __builtin_amdgcn_mfma_f32_32x32x16_bf16(a, bl,  acc, 0, 0, 0);
      acc = __builtin_amdgcn_mfma_f32_32x32x16_bf16(a, bl2, acc, 0, 0, 0);
    }
    // eval: lane owns column m=mB; 16 regs = 16 sample-rows of C
    float c2 = sgT[xi * NM + mB] * K2;                        // conflict-free
    float lp[NK];
#pragma unroll
    for (int k = 0; k < NK; ++k) lp[k] = 0.0f;
#pragma unroll
    for (int reg = 0; reg < 16; ++reg) {
      float base2 = acc[reg] * K2;
#pragma unroll
      for (int k = 0; k < NK; ++k) {
        float zb = fmaf(c2, (float)(2 * k - 7), base2);
        float e2 = EXP2(-fabsf(zb));
        lp[k] += fminf(zb, 0.0f) - LOG2(1.0f + e2);
      }
    }

    // reduction: f64 tree over all 1024 threads (covers all 256x64 (s,m) once)
    double v[NK];
#pragma unroll
    for (int k = 0; k < NK; ++k) v[k] = (double)lp[k];
#pragma unroll
    for (int off = 32; off >= 1; off >>= 1) {
#pragma unroll
      for (int k = 0; k < NK; ++k) v[k] += __shfl_down(v[k], off, 64);
    }
    int wv = tid >> 6, ln = tid & 63;
    if (ln == 0) {
#pragma unroll
      for (int k = 0; k < NK; ++k) red[wv][k] = v[k];
    }
    __syncthreads();
    if (tid < NK) {
      double sum = 0.0;
#pragma unroll
      for (int q = 0; q < 16; ++q) sum += red[q][tid];
      float ex = (float)(sum * 0.0027076061740622863);        // ln2/256
      float oldv = lqs[xi * LQP + tid];
      float newv = (1.0f - alpha) * oldv + alpha * ex;
      float mx = newv;
      mx = fmaxf(mx, __shfl_xor(mx, 1, 64));
      mx = fmaxf(mx, __shfl_xor(mx, 2, 64));
      mx = fmaxf(mx, __shfl_xor(mx, 4, 64));
      lqs[xi * LQP + tid] = newv - mx;
    }
    __syncthreads();
  }

  if (tid < NT * NK)
    lq_out[(size_t)n * NT * NK + tid] = lqs[(tid >> 3) * LQP + (tid & 7)];
}

extern "C" void kernel_launch(void* const* d_in, const int* in_sizes, int n_in,
                              void* d_out, int out_size, void* d_ws, size_t ws_size,
                              hipStream_t stream) {
  const float* log_qi = (const float*)d_in[0];
  const float* G      = (const float*)d_in[1];
  const float* s2r    = (const float*)d_in[2];
  const float* alpha  = (const float*)d_in[3];
  float* lq = (float*)d_out;
  mfs_fused<<<NB, 1024, 0, stream>>>(log_qi, G, s2r, alpha, lq);
}